// Round 4
// baseline (163.962 us; speedup 1.0000x reference)
//
#include <hip/hip_runtime.h>
#include <hip/hip_cooperative_groups.h>
#include <math.h>

namespace cg = cooperative_groups;

#define NB 8
#define NN 1024
#define NI 64
#define NO 32
#define NH 4
#define LOG2E 1.4426950408889634f

typedef _Float16 half8 __attribute__((ext_vector_type(8)));
typedef _Float16 half2v __attribute__((ext_vector_type(2)));
typedef float floatx4 __attribute__((ext_vector_type(4)));

#define VTP 1032   // vt row pitch in halfs

union SMem {
    struct { float xs[16 * 64]; float ws[4 * 64 * 36]; } a;                   // 40 KB
    struct { _Float16 vt[NO * VTP]; float srcs[NN]; float gps[NN]; float red[16]; } b;  // 74.3 KB
};

__global__ __launch_bounds__(256, 2) void k_fused(
    const float* __restrict__ x, const int* __restrict__ adj,
    const float* __restrict__ prior, const float* __restrict__ beta,
    const float* __restrict__ weight, const float* __restrict__ attn_src,
    const float* __restrict__ attn_dst, const float* __restrict__ bias,
    _Float16* __restrict__ projT,    // ws: [B,H,O,N] fp16
    float* __restrict__ src_s, float* __restrict__ dst_s, float* __restrict__ gp_,
    unsigned char* __restrict__ adjb,
    float* __restrict__ out)
{
    __shared__ SMem sm;
    const int t = threadIdx.x;
    const int blk = blockIdx.x;
    const int lane = t & 63, wave = t >> 6;

    // ================= Phase A: pack + projection + scores =================
    {
        const int b = blk >> 6, n0 = (blk & 63) * 16;
        #pragma unroll
        for (int k = 0; k < 2; ++k) {
            const int g = blk * 512 + k * 256 + t;
            const int4 v = ((const int4*)adj)[g];
            ((unsigned int*)adjb)[g] =
                (v.x ? 1u : 0u) | ((v.y ? 1u : 0u) << 8) |
                ((v.z ? 1u : 0u) << 16) | ((v.w ? 1u : 0u) << 24);
        }
        ((float4*)sm.a.xs)[t] = ((const float4*)(x + ((size_t)b * NN + n0) * NI))[t];
        #pragma unroll
        for (int k = 0; k < 8; ++k) {
            const int e = t + k * 256;
            const int h = e >> 9, rem = e & 511, i = rem >> 3, o4 = rem & 7;
            *(float4*)&sm.a.ws[h * 2304 + i * 36 + o4 * 4] =
                *(const float4*)(weight + (h * NI + i) * NO + o4 * 4);
        }
        __syncthreads();

        const int o4 = t & 7, h = (t >> 3) & 3, ng = t >> 5;
        const int o0 = o4 * 4, nl0 = ng * 2;
        float acc[2][4];
        #pragma unroll
        for (int r = 0; r < 2; ++r)
            #pragma unroll
            for (int oo = 0; oo < 4; ++oo) acc[r][oo] = 0.f;
        #pragma unroll 4
        for (int i = 0; i < NI; ++i) {
            const float4 wv = *(const float4*)&sm.a.ws[h * 2304 + i * 36 + o0];
            #pragma unroll
            for (int r = 0; r < 2; ++r) {
                const float xv = sm.a.xs[(nl0 + r) * 64 + i];
                acc[r][0] = fmaf(xv, wv.x, acc[r][0]);
                acc[r][1] = fmaf(xv, wv.y, acc[r][1]);
                acc[r][2] = fmaf(xv, wv.z, acc[r][2]);
                acc[r][3] = fmaf(xv, wv.w, acc[r][3]);
            }
        }
        const float4 bv  = *(const float4*)(bias + h * NO + o0);
        const float4 asv = *(const float4*)(attn_src + h * NO + o0);
        const float4 adv = *(const float4*)(attn_dst + h * NO + o0);
        const int bh = b * NH + h, gn0 = n0 + nl0;
        float ssum[2], dsum[2];
        #pragma unroll
        for (int r = 0; r < 2; ++r) {
            acc[r][0] += bv.x; acc[r][1] += bv.y;
            acc[r][2] += bv.z; acc[r][3] += bv.w;
            ssum[r] = acc[r][0]*asv.x + acc[r][1]*asv.y + acc[r][2]*asv.z + acc[r][3]*asv.w;
            dsum[r] = acc[r][0]*adv.x + acc[r][1]*adv.y + acc[r][2]*adv.z + acc[r][3]*adv.w;
        }
        #pragma unroll
        for (int oo = 0; oo < 4; ++oo) {
            half2v hv; hv[0] = (_Float16)acc[0][oo]; hv[1] = (_Float16)acc[1][oo];
            *(half2v*)(projT + ((size_t)(bh * NO + o0 + oo)) * NN + gn0) = hv;
        }
        #pragma unroll
        for (int msk = 1; msk <= 4; msk <<= 1) {
            #pragma unroll
            for (int r = 0; r < 2; ++r) {
                ssum[r] += __shfl_xor(ssum[r], msk, 64);
                dsum[r] += __shfl_xor(dsum[r], msk, 64);
            }
        }
        if (o4 == 0) {
            const float bx = beta[h];
            const float sp = fmaxf(bx, 0.f) + log1pf(__expf(-fabsf(bx)));
            #pragma unroll
            for (int r = 0; r < 2; ++r) {
                const int n = gn0 + r;
                src_s[bh * NN + n] = LOG2E * ssum[r];
                dst_s[bh * NN + n] = LOG2E * dsum[r];
                gp_[bh * NN + n]   = LOG2E * sp * prior[b * NN + n];
            }
        }
    }

    cg::this_grid().sync();

    // ================= Phase B: masked softmax + MFMA aggregation ==========
    {
        const int b = blk >> 6, h = (blk >> 4) & 3, dtile = blk & 15;
        const int bh = b * NH + h;
        const float4 s4 = ((const float4*)(src_s + bh * NN))[t];
        const float4 g4 = ((const float4*)(gp_ + bh * NN))[t];
        ((float4*)sm.b.srcs)[t] = s4;
        ((float4*)sm.b.gps)[t]  = g4;
        float s_l = fmaxf(fmaxf(s4.x, s4.y), fmaxf(s4.z, s4.w));
        float g_l = fmaxf(fmaxf(g4.x, g4.y), fmaxf(g4.z, g4.w));
        #pragma unroll
        for (int msk = 1; msk <= 32; msk <<= 1) {
            s_l = fmaxf(s_l, __shfl_xor(s_l, msk, 64));
            g_l = fmaxf(g_l, __shfl_xor(g_l, msk, 64));
        }
        if (lane == 0) { sm.b.red[wave * 2] = s_l; sm.b.red[wave * 2 + 1] = g_l; }
        const _Float16* ptrow = projT + (size_t)bh * NO * NN;
        #pragma unroll
        for (int k = 0; k < 16; ++k) {
            const int e = t + k * 256;
            const int o = e >> 7, sc8 = e & 127;
            *(half8*)&sm.b.vt[o * VTP + sc8 * 8] =
                *(const half8*)(ptrow + (size_t)o * NN + sc8 * 8);
        }
        __syncthreads();
        const float S = fmaxf(fmaxf(sm.b.red[0], sm.b.red[2]),
                              fmaxf(sm.b.red[4], sm.b.red[6]));
        const float G = fmaxf(fmaxf(sm.b.red[1], sm.b.red[3]),
                              fmaxf(sm.b.red[5], sm.b.red[7]));

        const int m = lane & 15, quad = lane >> 4;
        const int d = dtile * 64 + wave * 16 + m;
        const float dregl = dst_s[bh * NN + d];
        const float rmcl = fmaxf(dregl + S, 0.f) + G;   // >= every row score
        const unsigned char* adjr = adjb + (size_t)d * NN;

        floatx4 acc0 = {0.f, 0.f, 0.f, 0.f}, acc1 = {0.f, 0.f, 0.f, 0.f};
        float psum = 0.f;
        uint2 apre = *(const uint2*)(adjr + quad * 8);

        for (int st = 0; st < 32; ++st) {
            const uint2 acur = apre;
            if (st < 31) apre = *(const uint2*)(adjr + (st + 1) * 32 + quad * 8);
            const int sg = st * 32 + quad * 8;
            float sv[8], gv[8];
            *(float4*)&sv[0] = *(const float4*)&sm.b.srcs[sg];
            *(float4*)&sv[4] = *(const float4*)&sm.b.srcs[sg + 4];
            *(float4*)&gv[0] = *(const float4*)&sm.b.gps[sg];
            *(float4*)&gv[4] = *(const float4*)&sm.b.gps[sg + 4];
            half8 af;
            #pragma unroll
            for (int j = 0; j < 8; ++j) {
                const unsigned int bit =
                    ((j < 4 ? (acur.x >> (8 * j)) : (acur.y >> (8 * (j - 4)))) & 1u);
                const float ts = dregl + sv[j];
                const float lk = fmaxf(ts, 0.2f * ts);      // leaky in log2 domain
                const float e = exp2f(lk + (gv[j] - rmcl)); // arg <= 0
                const float p = bit ? e : 0.f;
                psum += p;
                af[j] = (_Float16)p;
            }
            const half8 b0 = *(const half8*)&sm.b.vt[m * VTP + sg];
            const half8 b1 = *(const half8*)&sm.b.vt[(16 + m) * VTP + sg];
            acc0 = __builtin_amdgcn_mfma_f32_16x16x32_f16(af, b0, acc0, 0, 0, 0);
            acc1 = __builtin_amdgcn_mfma_f32_16x16x32_f16(af, b1, acc1, 0, 0, 0);
        }
        psum += __shfl_xor(psum, 16, 64);
        psum += __shfl_xor(psum, 32, 64);

        #pragma unroll
        for (int r = 0; r < 4; ++r) {
            const int row = quad * 4 + r;
            const float lr = __shfl(psum, row, 64);
            const float inv = 1.f / fmaxf(lr, 1.1920929e-07f);
            float* go = out + ((size_t)(b * NN + dtile * 64 + wave * 16 + row)) * (NH * NO) + h * NO;
            go[m] = acc0[r] * inv;
            go[16 + m] = acc1[r] * inv;
        }
    }
}

extern "C" void kernel_launch(void* const* d_in, const int* in_sizes, int n_in,
                              void* d_out, int out_size, void* d_ws, size_t ws_size,
                              hipStream_t stream) {
    (void)in_sizes; (void)n_in; (void)out_size; (void)ws_size;
    const float* x        = (const float*)d_in[0];
    const int*   adj      = (const int*)d_in[1];
    const float* prior    = (const float*)d_in[2];
    const float* beta     = (const float*)d_in[3];
    const float* weight   = (const float*)d_in[4];
    const float* attn_src = (const float*)d_in[5];
    const float* attn_dst = (const float*)d_in[6];
    const float* bias     = (const float*)d_in[7];
    float* out = (float*)d_out;

    _Float16* projT = (_Float16*)d_ws;                          // 2 MB
    float* src_s = (float*)((char*)d_ws + (1 << 21));           // 128 KB each
    float* dst_s = src_s + NB * NH * NN;
    float* gpb   = dst_s + NB * NH * NN;
    unsigned char* adjb = (unsigned char*)(gpb + NB * NH * NN); // 1 MB

    void* args[] = {(void*)&x, (void*)&adj, (void*)&prior, (void*)&beta,
                    (void*)&weight, (void*)&attn_src, (void*)&attn_dst, (void*)&bias,
                    (void*)&projT, (void*)&src_s, (void*)&dst_s, (void*)&gpb,
                    (void*)&adjb, (void*)&out};
    hipLaunchCooperativeKernel((const void*)k_fused, dim3(512), dim3(256),
                               args, 0, stream);
}

// Round 5
// 104.836 us; speedup vs baseline: 1.5640x; 1.5640x over previous
//
#include <hip/hip_runtime.h>
#include <math.h>

#define NB 8
#define NN 1024
#define NI 64
#define NO 32
#define NH 4
#define LOG2E 1.4426950408889634f

typedef _Float16 half8 __attribute__((ext_vector_type(8)));
typedef _Float16 half2v __attribute__((ext_vector_type(2)));
typedef float floatx4 __attribute__((ext_vector_type(4)));

// ---------------- Kernel 1: pack + projection + scores (log2e domain) -------
// grid (32 ntiles, 8 b), 256 threads. Register tile 4n x 4o per thread.
__global__ __launch_bounds__(256) void k_proj(
    const float* __restrict__ x, const int* __restrict__ adj,
    const float* __restrict__ prior, const float* __restrict__ beta,
    const float* __restrict__ weight, const float* __restrict__ attn_src,
    const float* __restrict__ attn_dst, const float* __restrict__ bias,
    _Float16* __restrict__ projT,   // [B,H,O,N] fp16
    float* __restrict__ src_s, float* __restrict__ dst_s, float* __restrict__ gp_,
    unsigned char* __restrict__ adjb)
{
    __shared__ __align__(16) float xs[32 * 64];       // [n][i]
    __shared__ __align__(16) float ws[4 * 64 * 36];   // [h][i][o pad 36]
    const int t = threadIdx.x;
    const int ntile = blockIdx.x, b = blockIdx.y;
    const int n0b = ntile * 32;
    // adj pack: 1024 int4-groups per block
    #pragma unroll
    for (int k = 0; k < 4; ++k) {
        const int g = (b * 32 + ntile) * 1024 + k * 256 + t;
        const int4 v = ((const int4*)adj)[g];
        ((unsigned int*)adjb)[g] =
            (v.x ? 1u : 0u) | ((v.y ? 1u : 0u) << 8) |
            ((v.z ? 1u : 0u) << 16) | ((v.w ? 1u : 0u) << 24);
    }
    {
        const float4* xsrc = (const float4*)(x + ((size_t)b * NN + n0b) * NI);
        float4* xd = (float4*)xs;
        xd[t] = xsrc[t];
        xd[t + 256] = xsrc[t + 256];
    }
    #pragma unroll
    for (int k = 0; k < 8; ++k) {
        const int e = t + k * 256;
        const int h = e >> 9, rem = e & 511, i = rem >> 3, o4 = rem & 7;
        *(float4*)&ws[h * 2304 + i * 36 + o4 * 4] =
            *(const float4*)(weight + (h * NI + i) * NO + o4 * 4);
    }
    __syncthreads();

    const int o4 = t & 7, h = (t >> 3) & 3, ng = t >> 5;
    const int o0 = o4 * 4, nl0 = ng * 4;
    float acc[4][4];
    #pragma unroll
    for (int kn = 0; kn < 4; ++kn)
        #pragma unroll
        for (int oo = 0; oo < 4; ++oo) acc[kn][oo] = 0.f;

    #pragma unroll 4
    for (int i = 0; i < NI; ++i) {
        const float4 wv = *(const float4*)&ws[h * 2304 + i * 36 + o0];
        #pragma unroll
        for (int kn = 0; kn < 4; ++kn) {
            const float xv = xs[(nl0 + kn) * 64 + i];
            acc[kn][0] = fmaf(xv, wv.x, acc[kn][0]);
            acc[kn][1] = fmaf(xv, wv.y, acc[kn][1]);
            acc[kn][2] = fmaf(xv, wv.z, acc[kn][2]);
            acc[kn][3] = fmaf(xv, wv.w, acc[kn][3]);
        }
    }
    const float4 bv  = *(const float4*)(bias + h * NO + o0);
    const float4 asv = *(const float4*)(attn_src + h * NO + o0);
    const float4 adv = *(const float4*)(attn_dst + h * NO + o0);
    const int bh = b * NH + h;
    float ssum[4], dsum[4];
    #pragma unroll
    for (int kn = 0; kn < 4; ++kn) {
        acc[kn][0] += bv.x; acc[kn][1] += bv.y;
        acc[kn][2] += bv.z; acc[kn][3] += bv.w;
        ssum[kn] = acc[kn][0]*asv.x + acc[kn][1]*asv.y + acc[kn][2]*asv.z + acc[kn][3]*asv.w;
        dsum[kn] = acc[kn][0]*adv.x + acc[kn][1]*adv.y + acc[kn][2]*adv.z + acc[kn][3]*adv.w;
    }
    #pragma unroll
    for (int oo = 0; oo < 4; ++oo) {
        half2v h0, h1;
        h0[0] = (_Float16)acc[0][oo]; h0[1] = (_Float16)acc[1][oo];
        h1[0] = (_Float16)acc[2][oo]; h1[1] = (_Float16)acc[3][oo];
        _Float16* pp = projT + ((size_t)(bh * NO + o0 + oo)) * NN + n0b + nl0;
        *(half2v*)pp = h0;
        *(half2v*)(pp + 2) = h1;
    }
    #pragma unroll
    for (int msk = 1; msk <= 4; msk <<= 1) {
        #pragma unroll
        for (int kn = 0; kn < 4; ++kn) {
            ssum[kn] += __shfl_xor(ssum[kn], msk, 64);
            dsum[kn] += __shfl_xor(dsum[kn], msk, 64);
        }
    }
    if (o4 == 0) {
        const float bx = beta[h];
        const float sp = fmaxf(bx, 0.f) + log1pf(__expf(-fabsf(bx)));
        #pragma unroll
        for (int kn = 0; kn < 4; ++kn) {
            const int n = n0b + nl0 + kn;
            src_s[bh * NN + n] = LOG2E * ssum[kn];
            dst_s[bh * NN + n] = LOG2E * dsum[kn];
            gp_[bh * NN + n]   = LOG2E * sp * prior[b * NN + n];
        }
    }
}

// ---------------- Kernel 2: masked softmax + MFMA, source-split waves -------
// grid (64 rowtiles, 4 h, 8 b) = 2048 blocks, 256 threads = 4 waves.
// Each wave: same 16 dst rows, its own 256-source chunk (8 steps of 32).
// B-fragments read directly from global projT (L2-resident, no LDS tile).
__global__ __launch_bounds__(256, 4) void k_attn(
    const unsigned char* __restrict__ adjb,  // [N,N] bytes
    const _Float16* __restrict__ projT,      // [B,H,O,N]
    const float* __restrict__ src_s, const float* __restrict__ dst_s,
    const float* __restrict__ gp_,
    float* __restrict__ out)                 // [B,N,H*O]
{
    __shared__ __align__(16) float srcs[NN];
    __shared__ __align__(16) float gps[NN];
    __shared__ float red[8];
    __shared__ float part[4][16][33];   // [wave][d-row][o col, pad 33]
    __shared__ float ps[4][16];

    const int t = threadIdx.x;
    const int lane = t & 63, wave = t >> 6;
    const int rowtile = blockIdx.x, h = blockIdx.y, b = blockIdx.z;
    const int bh = b * NH + h;

    const float4 s4 = ((const float4*)(src_s + bh * NN))[t];
    const float4 g4 = ((const float4*)(gp_ + bh * NN))[t];
    ((float4*)srcs)[t] = s4;
    ((float4*)gps)[t]  = g4;
    float s_l = fmaxf(fmaxf(s4.x, s4.y), fmaxf(s4.z, s4.w));
    float g_l = fmaxf(fmaxf(g4.x, g4.y), fmaxf(g4.z, g4.w));
    #pragma unroll
    for (int msk = 1; msk <= 32; msk <<= 1) {
        s_l = fmaxf(s_l, __shfl_xor(s_l, msk, 64));
        g_l = fmaxf(g_l, __shfl_xor(g_l, msk, 64));
    }
    if (lane == 0) { red[wave * 2] = s_l; red[wave * 2 + 1] = g_l; }
    __syncthreads();
    const float S = fmaxf(fmaxf(red[0], red[2]), fmaxf(red[4], red[6]));
    const float G = fmaxf(fmaxf(red[1], red[3]), fmaxf(red[5], red[7]));

    const int m = lane & 15, quad = lane >> 4;
    const int d = rowtile * 16 + m;
    const float dregl = dst_s[bh * NN + d];
    const float rmcl = fmaxf(dregl + S, 0.f) + G;   // >= every row score (log2)
    const unsigned char* adjr = adjb + (size_t)d * NN;
    const _Float16* ptr0 = projT + (size_t)(bh * NO + m) * NN;
    const _Float16* ptr1 = ptr0 + 16 * NN;

    floatx4 acc0 = {0.f, 0.f, 0.f, 0.f}, acc1 = {0.f, 0.f, 0.f, 0.f};
    float psum = 0.f;
    int sg = wave * 256 + quad * 8;
    uint2  aa  = *(const uint2*)(adjr + sg);
    half8  vb0 = *(const half8*)(ptr0 + sg);
    half8  vb1 = *(const half8*)(ptr1 + sg);

    #pragma unroll
    for (int st = 0; st < 8; ++st) {
        const uint2 ac = aa;
        const half8 b0 = vb0, b1 = vb1;
        const int sgc = sg;
        if (st < 7) {                 // prefetch next step
            sg += 32;
            aa  = *(const uint2*)(adjr + sg);
            vb0 = *(const half8*)(ptr0 + sg);
            vb1 = *(const half8*)(ptr1 + sg);
        }
        float sv[8], gv[8];
        *(float4*)&sv[0] = *(const float4*)&srcs[sgc];
        *(float4*)&sv[4] = *(const float4*)&srcs[sgc + 4];
        *(float4*)&gv[0] = *(const float4*)&gps[sgc];
        *(float4*)&gv[4] = *(const float4*)&gps[sgc + 4];
        float p[8];
        #pragma unroll
        for (int j = 0; j < 8; ++j) {
            const unsigned int bit =
                ((j < 4 ? (ac.x >> (8 * j)) : (ac.y >> (8 * (j - 4)))) & 1u);
            const float ts = dregl + sv[j];
            const float lk = fmaxf(ts, 0.2f * ts);          // leaky (log2 dom)
            const float arg = bit ? (lk + gv[j] - rmcl) : -1e30f;
            p[j] = exp2f(arg);                              // arg <= 0
            psum += p[j];
        }
        half8 af;
        #pragma unroll
        for (int j = 0; j < 8; ++j) af[j] = (_Float16)p[j];
        acc0 = __builtin_amdgcn_mfma_f32_16x16x32_f16(af, b0, acc0, 0, 0, 0);
        acc1 = __builtin_amdgcn_mfma_f32_16x16x32_f16(af, b1, acc1, 0, 0, 0);
    }
    psum += __shfl_xor(psum, 16, 64);
    psum += __shfl_xor(psum, 32, 64);

    #pragma unroll
    for (int r = 0; r < 4; ++r) {     // C layout: row=quad*4+r (d), col=m (o)
        part[wave][quad * 4 + r][m]      = acc0[r];
        part[wave][quad * 4 + r][16 + m] = acc1[r];
    }
    if (quad == 0) ps[wave][m] = psum;
    __syncthreads();

    // combine 4 source-chunk partials, normalize, write
    const int row = t >> 4, col = t & 15;
    const float denom = ps[0][row] + ps[1][row] + ps[2][row] + ps[3][row];
    const float inv = 1.f / fmaxf(denom, 1.1920929e-07f);
    const float v0 = part[0][row][col] + part[1][row][col] +
                     part[2][row][col] + part[3][row][col];
    const float v1 = part[0][row][16 + col] + part[1][row][16 + col] +
                     part[2][row][16 + col] + part[3][row][16 + col];
    float* go = out + ((size_t)(b * NN + rowtile * 16 + row)) * (NH * NO) + h * NO;
    go[col]      = v0 * inv;
    go[16 + col] = v1 * inv;
}

extern "C" void kernel_launch(void* const* d_in, const int* in_sizes, int n_in,
                              void* d_out, int out_size, void* d_ws, size_t ws_size,
                              hipStream_t stream) {
    (void)in_sizes; (void)n_in; (void)out_size; (void)ws_size;
    const float* x        = (const float*)d_in[0];
    const int*   adj      = (const int*)d_in[1];
    const float* prior    = (const float*)d_in[2];
    const float* beta     = (const float*)d_in[3];
    const float* weight   = (const float*)d_in[4];
    const float* attn_src = (const float*)d_in[5];
    const float* attn_dst = (const float*)d_in[6];
    const float* bias     = (const float*)d_in[7];
    float* out = (float*)d_out;

    _Float16* projT = (_Float16*)d_ws;                          // 2 MB
    float* src_s = (float*)((char*)d_ws + (1 << 21));           // 128 KB each
    float* dst_s = src_s + NB * NH * NN;
    float* gpb   = dst_s + NB * NH * NN;
    unsigned char* adjb = (unsigned char*)(gpb + NB * NH * NN); // 1 MB

    hipLaunchKernelGGL(k_proj, dim3(32, 8), dim3(256), 0, stream,
                       x, adj, prior, beta, weight, attn_src, attn_dst, bias,
                       projT, src_s, dst_s, gpb, adjb);
    hipLaunchKernelGGL(k_attn, dim3(64, 4, 8), dim3(256), 0, stream,
                       adjb, projT, src_s, dst_s, gpb, out);
}

// Round 7
// 96.769 us; speedup vs baseline: 1.6944x; 1.0834x over previous
//
#include <hip/hip_runtime.h>
#include <math.h>

#define NB 8
#define NN 1024
#define NI 64
#define NO 32
#define NH 4
#define LOG2E 1.4426950408889634f

typedef _Float16 half8 __attribute__((ext_vector_type(8)));
typedef _Float16 half4v __attribute__((ext_vector_type(4)));
typedef float floatx4 __attribute__((ext_vector_type(4)));

// ---------------- Kernel 1: pack + projection + scores (log2e domain) -------
// grid (32 ntiles, 8 b), 256 threads. Register tile 4n x 4o per thread.
__global__ __launch_bounds__(256) void k_proj(
    const float* __restrict__ x, const int* __restrict__ adj,
    const float* __restrict__ prior, const float* __restrict__ beta,
    const float* __restrict__ weight, const float* __restrict__ attn_src,
    const float* __restrict__ attn_dst, const float* __restrict__ bias,
    _Float16* __restrict__ projT,   // [B,H,O,N] fp16
    float* __restrict__ src_s, float* __restrict__ dst_s, float* __restrict__ gp_,
    unsigned char* __restrict__ adjb)
{
    __shared__ __align__(16) float xs[32 * 64];       // [n][i]
    __shared__ __align__(16) float ws[4 * 64 * 36];   // [h][i][o pad 36]
    const int t = threadIdx.x;
    const int ntile = blockIdx.x, b = blockIdx.y;
    const int n0b = ntile * 32;
    // adj pack: 1024 int4-groups per block
    #pragma unroll
    for (int k = 0; k < 4; ++k) {
        const int g = (b * 32 + ntile) * 1024 + k * 256 + t;
        const int4 v = ((const int4*)adj)[g];
        ((unsigned int*)adjb)[g] =
            (v.x ? 1u : 0u) | ((v.y ? 1u : 0u) << 8) |
            ((v.z ? 1u : 0u) << 16) | ((v.w ? 1u : 0u) << 24);
    }
    {
        const float4* xsrc = (const float4*)(x + ((size_t)b * NN + n0b) * NI);
        float4* xd = (float4*)xs;
        xd[t] = xsrc[t];
        xd[t + 256] = xsrc[t + 256];
    }
    #pragma unroll
    for (int k = 0; k < 8; ++k) {
        const int e = t + k * 256;
        const int h = e >> 9, rem = e & 511, i = rem >> 3, o4 = rem & 7;
        *(float4*)&ws[h * 2304 + i * 36 + o4 * 4] =
            *(const float4*)(weight + (h * NI + i) * NO + o4 * 4);
    }
    __syncthreads();

    const int o4 = t & 7, h = (t >> 3) & 3, ng = t >> 5;
    const int o0 = o4 * 4, nl0 = ng * 4;
    float acc[4][4];
    #pragma unroll
    for (int kn = 0; kn < 4; ++kn)
        #pragma unroll
        for (int oo = 0; oo < 4; ++oo) acc[kn][oo] = 0.f;

    #pragma unroll 4
    for (int i = 0; i < NI; ++i) {
        const float4 wv = *(const float4*)&ws[h * 2304 + i * 36 + o0];
        #pragma unroll
        for (int kn = 0; kn < 4; ++kn) {
            const float xv = xs[(nl0 + kn) * 64 + i];
            acc[kn][0] = fmaf(xv, wv.x, acc[kn][0]);
            acc[kn][1] = fmaf(xv, wv.y, acc[kn][1]);
            acc[kn][2] = fmaf(xv, wv.z, acc[kn][2]);
            acc[kn][3] = fmaf(xv, wv.w, acc[kn][3]);
        }
    }
    const float4 bv  = *(const float4*)(bias + h * NO + o0);
    const float4 asv = *(const float4*)(attn_src + h * NO + o0);
    const float4 adv = *(const float4*)(attn_dst + h * NO + o0);
    const int bh = b * NH + h;
    float ssum[4], dsum[4];
    #pragma unroll
    for (int kn = 0; kn < 4; ++kn) {
        acc[kn][0] += bv.x; acc[kn][1] += bv.y;
        acc[kn][2] += bv.z; acc[kn][3] += bv.w;
        ssum[kn] = acc[kn][0]*asv.x + acc[kn][1]*asv.y + acc[kn][2]*asv.z + acc[kn][3]*asv.w;
        dsum[kn] = acc[kn][0]*adv.x + acc[kn][1]*adv.y + acc[kn][2]*adv.z + acc[kn][3]*adv.w;
    }
    #pragma unroll
    for (int oo = 0; oo < 4; ++oo) {   // 4 consecutive n per 8B store
        half4v hv;
        hv[0] = (_Float16)acc[0][oo]; hv[1] = (_Float16)acc[1][oo];
        hv[2] = (_Float16)acc[2][oo]; hv[3] = (_Float16)acc[3][oo];
        *(half4v*)(projT + ((size_t)(bh * NO + o0 + oo)) * NN + n0b + nl0) = hv;
    }
    #pragma unroll
    for (int msk = 1; msk <= 4; msk <<= 1) {
        #pragma unroll
        for (int kn = 0; kn < 4; ++kn) {
            ssum[kn] += __shfl_xor(ssum[kn], msk, 64);
            dsum[kn] += __shfl_xor(dsum[kn], msk, 64);
        }
    }
    if (o4 == 0) {
        const float bx = beta[h];
        const float sp = fmaxf(bx, 0.f) + log1pf(__expf(-fabsf(bx)));
        #pragma unroll
        for (int kn = 0; kn < 4; ++kn) {
            const int n = n0b + nl0 + kn;
            src_s[bh * NN + n] = LOG2E * ssum[kn];
            dst_s[bh * NN + n] = LOG2E * dsum[kn];
            gp_[bh * NN + n]   = LOG2E * sp * prior[b * NN + n];
        }
    }
}

// ---------------- Kernel 2: masked softmax + MFMA, 32 rows/block ------------
// 1024 blocks (1D, XCD-swizzled: blk%8 = b -> same (b,h) slice on same XCD),
// 256 threads = 4 waves; each wave: 32 dst rows x its 256-source chunk.
// psum via ones-column MFMA; B-frags direct from L2-resident projT.
__global__ __launch_bounds__(256, 4) void k_attn(
    const unsigned char* __restrict__ adjb,  // [N,N] bytes
    const _Float16* __restrict__ projT,      // [B,H,O,N]
    const float* __restrict__ src_s, const float* __restrict__ dst_s,
    const float* __restrict__ gp_,
    float* __restrict__ out)                 // [B,N,H*O]
{
    __shared__ __align__(16) float srcs[NN];
    __shared__ __align__(16) float srcs2[NN];   // 0.2 * srcs
    __shared__ __align__(16) float gps[NN];
    __shared__ float red[8];
    __shared__ float part[4][32][33];           // [wave][d-row][o col]
    __shared__ float ps[4][32];

    const int t = threadIdx.x;
    const int lane = t & 63, wave = t >> 6;
    const int blk = blockIdx.x;
    const int rowtile = blk >> 5, h = (blk >> 3) & 3, b = blk & 7;
    const int bh = b * NH + h;
    const int d0 = rowtile * 32;

    const float4 s4 = ((const float4*)(src_s + bh * NN))[t];
    const float4 g4 = ((const float4*)(gp_ + bh * NN))[t];
    ((float4*)srcs)[t] = s4;
    float4 s42; s42.x = 0.2f * s4.x; s42.y = 0.2f * s4.y;
    s42.z = 0.2f * s4.z; s42.w = 0.2f * s4.w;
    ((float4*)srcs2)[t] = s42;
    ((float4*)gps)[t] = g4;
    float s_l = fmaxf(fmaxf(s4.x, s4.y), fmaxf(s4.z, s4.w));
    float g_l = fmaxf(fmaxf(g4.x, g4.y), fmaxf(g4.z, g4.w));
    #pragma unroll
    for (int msk = 1; msk <= 32; msk <<= 1) {
        s_l = fmaxf(s_l, __shfl_xor(s_l, msk, 64));
        g_l = fmaxf(g_l, __shfl_xor(g_l, msk, 64));
    }
    if (lane == 0) { red[wave * 2] = s_l; red[wave * 2 + 1] = g_l; }
    __syncthreads();
    const float S = fmaxf(fmaxf(red[0], red[2]), fmaxf(red[4], red[6]));
    const float G = fmaxf(fmaxf(red[1], red[3]), fmaxf(red[5], red[7]));

    const int m = lane & 15, quad = lane >> 4;
    const int dlo = d0 + m, dhi = d0 + 16 + m;
    const float drl = dst_s[bh * NN + dlo];
    const float drh = dst_s[bh * NN + dhi];
    const float Rlo = fmaxf(drl + S, 0.f) + G;   // upper bound, log2 domain
    const float Rhi = fmaxf(drh + S, 0.f) + G;
    const float c1l = drl - Rlo, c2l = 0.2f * drl - Rlo;
    const float c1h = drh - Rhi, c2h = 0.2f * drh - Rhi;
    const unsigned char* arl = adjb + (size_t)dlo * NN;
    const unsigned char* arh = adjb + (size_t)dhi * NN;
    const _Float16* ptr0 = projT + (size_t)(bh * NO + m) * NN;
    const _Float16* ptr1 = ptr0 + 16 * NN;

    half8 onesv;
    #pragma unroll
    for (int j = 0; j < 8; ++j) onesv[j] = (_Float16)1.0f;

    floatx4 aLL = {0,0,0,0}, aLH = {0,0,0,0}, aHL = {0,0,0,0}, aHH = {0,0,0,0};
    floatx4 pL = {0,0,0,0}, pH = {0,0,0,0};

    int sg = wave * 256 + quad * 8;
    uint2 al = *(const uint2*)(arl + sg);
    uint2 ah = *(const uint2*)(arh + sg);
    half8 vb0 = *(const half8*)(ptr0 + sg);
    half8 vb1 = *(const half8*)(ptr1 + sg);

    #pragma unroll
    for (int st = 0; st < 8; ++st) {
        const uint2 acl = al, ach = ah;
        const half8 b0 = vb0, b1 = vb1;
        const int sgc = sg;
        if (st < 7) {                 // prefetch next step
            sg += 32;
            al = *(const uint2*)(arl + sg);
            ah = *(const uint2*)(arh + sg);
            vb0 = *(const half8*)(ptr0 + sg);
            vb1 = *(const half8*)(ptr1 + sg);
        }
        float sv[8], s2[8], gv[8];
        *(float4*)&sv[0] = *(const float4*)&srcs[sgc];
        *(float4*)&sv[4] = *(const float4*)&srcs[sgc + 4];
        *(float4*)&s2[0] = *(const float4*)&srcs2[sgc];
        *(float4*)&s2[4] = *(const float4*)&srcs2[sgc + 4];
        *(float4*)&gv[0] = *(const float4*)&gps[sgc];
        *(float4*)&gv[4] = *(const float4*)&gps[sgc + 4];
        half8 afl, afh;
        #pragma unroll
        for (int j = 0; j < 8; ++j) {
            const unsigned int bl_ =
                ((j < 4 ? (acl.x >> (8 * j)) : (acl.y >> (8 * (j - 4)))) & 1u);
            const unsigned int bh_ =
                ((j < 4 ? (ach.x >> (8 * j)) : (ach.y >> (8 * (j - 4)))) & 1u);
            const float argl = fmaxf(sv[j] + c1l, s2[j] + c2l) + gv[j];
            const float argh = fmaxf(sv[j] + c1h, s2[j] + c2h) + gv[j];
            afl[j] = (_Float16)exp2f(bl_ ? argl : -1e30f);   // arg <= 0 always
            afh[j] = (_Float16)exp2f(bh_ ? argh : -1e30f);
        }
        aLL = __builtin_amdgcn_mfma_f32_16x16x32_f16(afl, b0, aLL, 0, 0, 0);
        aLH = __builtin_amdgcn_mfma_f32_16x16x32_f16(afl, b1, aLH, 0, 0, 0);
        aHL = __builtin_amdgcn_mfma_f32_16x16x32_f16(afh, b0, aHL, 0, 0, 0);
        aHH = __builtin_amdgcn_mfma_f32_16x16x32_f16(afh, b1, aHH, 0, 0, 0);
        pL  = __builtin_amdgcn_mfma_f32_16x16x32_f16(afl, onesv, pL, 0, 0, 0);
        pH  = __builtin_amdgcn_mfma_f32_16x16x32_f16(afh, onesv, pH, 0, 0, 0);
    }

    // C layout: row = quad*4+r, col = m
    #pragma unroll
    for (int r = 0; r < 4; ++r) {
        const int row = quad * 4 + r;
        part[wave][row][m]           = aLL[r];
        part[wave][row][16 + m]      = aLH[r];
        part[wave][16 + row][m]      = aHL[r];
        part[wave][16 + row][16 + m] = aHH[r];
    }
    if (m == 0) {
        #pragma unroll
        for (int r = 0; r < 4; ++r) {
            ps[wave][quad * 4 + r]      = pL[r];
            ps[wave][16 + quad * 4 + r] = pH[r];
        }
    }
    __syncthreads();

    // combine 4 source-chunk partials, normalize, write (float4 per thread)
    const int row = t >> 3, c0 = (t & 7) * 4;
    const float denom = ps[0][row] + ps[1][row] + ps[2][row] + ps[3][row];
    const float inv = 1.f / fmaxf(denom, 1.1920929e-07f);
    float4 r4;
    float* rp = &r4.x;
    #pragma unroll
    for (int i = 0; i < 4; ++i) {
        const int c = c0 + i;
        rp[i] = (part[0][row][c] + part[1][row][c] +
                 part[2][row][c] + part[3][row][c]) * inv;
    }
    *(float4*)(out + ((size_t)(b * NN + d0 + row)) * (NH * NO) + h * NO + c0) = r4;
}

extern "C" void kernel_launch(void* const* d_in, const int* in_sizes, int n_in,
                              void* d_out, int out_size, void* d_ws, size_t ws_size,
                              hipStream_t stream) {
    (void)in_sizes; (void)n_in; (void)out_size; (void)ws_size;
    const float* x        = (const float*)d_in[0];
    const int*   adj      = (const int*)d_in[1];
    const float* prior    = (const float*)d_in[2];
    const float* beta     = (const float*)d_in[3];
    const float* weight   = (const float*)d_in[4];
    const float* attn_src = (const float*)d_in[5];
    const float* attn_dst = (const float*)d_in[6];
    const float* bias     = (const float*)d_in[7];
    float* out = (float*)d_out;

    _Float16* projT = (_Float16*)d_ws;                          // 2 MB
    float* src_s = (float*)((char*)d_ws + (1 << 21));           // 128 KB each
    float* dst_s = src_s + NB * NH * NN;
    float* gpb   = dst_s + NB * NH * NN;
    unsigned char* adjb = (unsigned char*)(gpb + NB * NH * NN); // 1 MB

    hipLaunchKernelGGL(k_proj, dim3(32, 8), dim3(256), 0, stream,
                       x, adj, prior, beta, weight, attn_src, attn_dst, bias,
                       projT, src_s, dst_s, gpb, adjb);
    hipLaunchKernelGGL(k_attn, dim3(1024), dim3(256), 0, stream,
                       adjb, projT, src_s, dst_s, gpb, out);
}